// Round 1
// baseline (873.394 us; speedup 1.0000x reference)
//
#include <hip/hip_runtime.h>
#include <cstdint>
#include <cstddef>

typedef int v4i __attribute__((ext_vector_type(4)));

// ---------------------------------------------------------------------------
// async global->LDS 16B copy. LDS dest is wave-uniform base + lane*16.
// ---------------------------------------------------------------------------
__device__ __forceinline__ void load_lds16(const void* g, void* l) {
    __builtin_amdgcn_global_load_lds(
        (const __attribute__((address_space(1))) void*)g,
        (__attribute__((address_space(3))) void*)l,
        16, 0, 0);
}

// ---------------------------------------------------------------------------
// Kernel 1: sum of |W| (double accumulation for deterministic-enough mean;
// a ternary rounding-boundary flip is worth ~0.09 absmax, threshold 0.105)
// ---------------------------------------------------------------------------
__global__ void wabs_sum_kernel(const float4* __restrict__ w4,
                                double* __restrict__ acc, int n4) {
    double s = 0.0;
    for (int i = blockIdx.x * blockDim.x + threadIdx.x; i < n4;
         i += gridDim.x * blockDim.x) {
        float4 v = w4[i];
        s += (double)fabsf(v.x) + (double)fabsf(v.y) +
             (double)fabsf(v.z) + (double)fabsf(v.w);
    }
    for (int o = 32; o > 0; o >>= 1) s += __shfl_down(s, o);
    __shared__ double sb[4];
    const int wid = threadIdx.x >> 6, lane = threadIdx.x & 63;
    if (lane == 0) sb[wid] = s;
    __syncthreads();
    if (threadIdx.x == 0) atomicAdd(acc, sb[0] + sb[1] + sb[2] + sb[3]);
}

__device__ __forceinline__ float sw_from_sum(const double* sump, int n) {
    float mean = (float)(*sump / (double)n);
    return 1.0f / fmaxf(mean, 1e-5f);   // sw = 1/max(mean|W|, Q_EPS)
}

// ---------------------------------------------------------------------------
// Kernel 2: ternary weight quantization -> int8 {-1,0,1}, row-major [O,K]
// ---------------------------------------------------------------------------
__global__ void wquant_kernel(const float4* __restrict__ w4,
                              const double* __restrict__ sump,
                              char4* __restrict__ wq4, int n4, int n) {
    const float s = sw_from_sum(sump, n);
    int i = blockIdx.x * blockDim.x + threadIdx.x;
    if (i >= n4) return;
    float4 v = w4[i];
    char4 q;
    q.x = (signed char)(int)fmaxf(-1.f, fminf(1.f, rintf(v.x * s)));
    q.y = (signed char)(int)fmaxf(-1.f, fminf(1.f, rintf(v.y * s)));
    q.z = (signed char)(int)fmaxf(-1.f, fminf(1.f, rintf(v.z * s)));
    q.w = (signed char)(int)fmaxf(-1.f, fminf(1.f, rintf(v.w * s)));
    wq4[i] = q;
}

// ---------------------------------------------------------------------------
// Kernel 3: fused RMSNorm + per-token int8 act quant.
// One block per token row (D=4096, 256 thr * 16 elems, kept in registers).
// Also writes rscale[m] = 1/(sx*sw) for the GEMM epilogue.
// ---------------------------------------------------------------------------
__global__ __launch_bounds__(256) void act_quant_kernel(
    const float* __restrict__ x, const float* __restrict__ nw,
    const double* __restrict__ sump, int wcount,
    signed char* __restrict__ hq, float* __restrict__ rscale, int D) {
    const int m = blockIdx.x;
    const int t = threadIdx.x;
    const float4* xr  = (const float4*)(x + (size_t)m * D);
    const float4* nw4 = (const float4*)nw;

    float4 v[4];
    float ss = 0.f;
#pragma unroll
    for (int i = 0; i < 4; ++i) {
        v[i] = xr[t + 256 * i];
        ss += v[i].x * v[i].x + v[i].y * v[i].y +
              v[i].z * v[i].z + v[i].w * v[i].w;
    }
    for (int o = 32; o > 0; o >>= 1) ss += __shfl_down(ss, o);
    __shared__ float sb[4];
    const int wid = t >> 6, lane = t & 63;
    if (lane == 0) sb[wid] = ss;
    __syncthreads();
    const float var  = (sb[0] + sb[1] + sb[2] + sb[3]) / (float)D;
    const float rstd = (float)(1.0 / sqrt((double)var + 1e-5));
    __syncthreads();   // sb re-used below

    float mx = 0.f;
#pragma unroll
    for (int i = 0; i < 4; ++i) {
        float4 g = nw4[t + 256 * i];
        v[i].x = v[i].x * rstd * g.x;
        v[i].y = v[i].y * rstd * g.y;
        v[i].z = v[i].z * rstd * g.z;
        v[i].w = v[i].w * rstd * g.w;
        mx = fmaxf(mx, fmaxf(fmaxf(fabsf(v[i].x), fabsf(v[i].y)),
                             fmaxf(fabsf(v[i].z), fabsf(v[i].w))));
    }
    for (int o = 32; o > 0; o >>= 1) mx = fmaxf(mx, __shfl_down(mx, o));
    if (lane == 0) sb[wid] = mx;
    __syncthreads();
    const float mxa   = fmaxf(fmaxf(sb[0], sb[1]), fmaxf(sb[2], sb[3]));
    const float scale = 127.0f / fmaxf(mxa, 1e-5f);

    char4* hq4 = (char4*)(hq + (size_t)m * D);
#pragma unroll
    for (int i = 0; i < 4; ++i) {
        char4 q;
        q.x = (signed char)(int)fmaxf(-128.f, fminf(127.f, rintf(v[i].x * scale)));
        q.y = (signed char)(int)fmaxf(-128.f, fminf(127.f, rintf(v[i].y * scale)));
        q.z = (signed char)(int)fmaxf(-128.f, fminf(127.f, rintf(v[i].z * scale)));
        q.w = (signed char)(int)fmaxf(-128.f, fminf(127.f, rintf(v[i].w * scale)));
        hq4[t + 256 * i] = q;
    }
    if (t == 0) {
        const float sw = sw_from_sum(sump, wcount);
        rscale[m] = 1.0f / (scale * sw);
    }
}

// ---------------------------------------------------------------------------
// Kernel 4: int8 GEMM  C[m,n] = sum_k A[m,k]*B[n,k]  (both K-contiguous, NT)
// 128x128 tile, BK=64, 4 waves of 64x64, mfma_i32_16x16x64_i8,
// global_load_lds width-16 staging (m97 structure).
// Epilogue: out = (float)C * rscale[m].
// ---------------------------------------------------------------------------
__global__ __launch_bounds__(256) void gemm_i8_kernel(
    const signed char* __restrict__ A, const signed char* __restrict__ B,
    const float* __restrict__ rscale, float* __restrict__ out,
    int M, int N, int K) {
    constexpr int BM = 128, BN = 128, BK = 64;
    __shared__ signed char As[BM * BK];   // 8 KiB, row-major [128][64]
    __shared__ signed char Bs[BN * BK];   // 8 KiB

    const int tid  = threadIdx.x;
    const int wave = tid >> 6;
    const int lane = tid & 63;
    const int wm   = wave >> 1;           // 0..1 : wave row in 2x2 wave grid
    const int wn   = wave & 1;            // 0..1
    const int quad = lane >> 4;           // 0..3
    const int r    = lane & 15;           // 0..15

    const int m0 = blockIdx.y * BM;
    const int n0 = blockIdx.x * BN;

    v4i acc[4][4] = {};

    // staging: each wave fills 2 chunks of 1024B in As and Bs.
    // chunk = wave*2+c covers rows [chunk*16, chunk*16+16), lane L -> row
    // chunk*16 + L/4, kbyte (L%4)*16; LDS dest = base + L*16 (HW scatter).
    const int srow = lane >> 2;           // 0..15
    const int skb  = (lane & 3) * 16;     // 0,16,32,48
    const signed char* aSrc = A + (size_t)(m0 + wave * 32 + srow) * K + skb;
    const signed char* bSrc = B + (size_t)(n0 + wave * 32 + srow) * K + skb;

    for (int k0 = 0; k0 < K; k0 += BK) {
#pragma unroll
        for (int c = 0; c < 2; ++c) {
            load_lds16(aSrc + (size_t)(c * 16) * K + k0, &As[(wave * 2 + c) * 1024]);
            load_lds16(bSrc + (size_t)(c * 16) * K + k0, &Bs[(wave * 2 + c) * 1024]);
        }
        __syncthreads();   // drains vmcnt (global_load_lds) + barrier

        v4i af[4], bf[4];
#pragma unroll
        for (int mi = 0; mi < 4; ++mi)
            af[mi] = *(const v4i*)&As[(wm * 64 + mi * 16 + r) * BK + quad * 16];
#pragma unroll
        for (int ni = 0; ni < 4; ++ni)
            bf[ni] = *(const v4i*)&Bs[(wn * 64 + ni * 16 + r) * BK + quad * 16];

#pragma unroll
        for (int mi = 0; mi < 4; ++mi)
#pragma unroll
            for (int ni = 0; ni < 4; ++ni)
                acc[mi][ni] = __builtin_amdgcn_mfma_i32_16x16x64_i8(
                    af[mi], bf[ni], acc[mi][ni], 0, 0, 0);
        __syncthreads();
    }

    // epilogue: C/D layout col = lane&15, row = quad*4 + reg
#pragma unroll
    for (int mi = 0; mi < 4; ++mi) {
#pragma unroll
        for (int reg = 0; reg < 4; ++reg) {
            const int m  = m0 + wm * 64 + mi * 16 + quad * 4 + reg;
            const float rs = rscale[m];
            const size_t rowoff = (size_t)m * N + n0 + wn * 64 + r;
#pragma unroll
            for (int ni = 0; ni < 4; ++ni)
                out[rowoff + ni * 16] = (float)acc[mi][ni][reg] * rs;
        }
    }
}

// ---------------------------------------------------------------------------
extern "C" void kernel_launch(void* const* d_in, const int* in_sizes, int n_in,
                              void* d_out, int out_size, void* d_ws, size_t ws_size,
                              hipStream_t stream) {
    const float* x  = (const float*)d_in[0];   // [B,S,D] fp32
    const float* nw = (const float*)d_in[1];   // [D]
    const float* w  = (const float*)d_in[2];   // [O,D]
    const int D = in_sizes[1];
    const int M = in_sizes[0] / D;             // B*S tokens
    const int O = in_sizes[2] / D;
    const int WN = O * D;                      // weight element count

    char* ws = (char*)d_ws;
    double* d_sum    = (double*)(ws + 0);
    float*  d_rscale = (float*)(ws + 128);
    size_t off = 128 + (size_t)M * sizeof(float);
    off = (off + 255) & ~(size_t)255;
    signed char* d_wq = (signed char*)(ws + off);
    off += (size_t)WN;
    off = (off + 255) & ~(size_t)255;
    signed char* d_hq = (signed char*)(ws + off);

    hipMemsetAsync(d_sum, 0, sizeof(double), stream);

    wabs_sum_kernel<<<4096, 256, 0, stream>>>((const float4*)w, d_sum, WN / 4);

    wquant_kernel<<<(WN / 4 + 255) / 256, 256, 0, stream>>>(
        (const float4*)w, d_sum, (char4*)d_wq, WN / 4, WN);

    act_quant_kernel<<<M, 256, 0, stream>>>(x, nw, d_sum, WN, d_hq, d_rscale, D);

    dim3 grid(O / 128, M / 128);
    gemm_i8_kernel<<<grid, 256, 0, stream>>>(d_hq, d_wq, d_rscale,
                                             (float*)d_out, M, O, D);
}

// Round 2
// 802.331 us; speedup vs baseline: 1.0886x; 1.0886x over previous
//
#include <hip/hip_runtime.h>
#include <cstdint>
#include <cstddef>

typedef int v4i  __attribute__((ext_vector_type(4)));
typedef int v16i __attribute__((ext_vector_type(16)));

// ---------------------------------------------------------------------------
// async global->LDS 16B copy. LDS dest is wave-uniform base + lane*16.
// ---------------------------------------------------------------------------
__device__ __forceinline__ void load_lds16(const void* g, void* l) {
    __builtin_amdgcn_global_load_lds(
        (const __attribute__((address_space(1))) void*)g,
        (__attribute__((address_space(3))) void*)l,
        16, 0, 0);
}

// ---------------------------------------------------------------------------
// Kernel 1: sum of |W| (double accumulation; a ternary rounding-boundary flip
// is worth ~0.09 absmax vs threshold 0.105, so keep the mean exact)
// ---------------------------------------------------------------------------
__global__ void wabs_sum_kernel(const float4* __restrict__ w4,
                                double* __restrict__ acc, int n4) {
    double s = 0.0;
    for (int i = blockIdx.x * blockDim.x + threadIdx.x; i < n4;
         i += gridDim.x * blockDim.x) {
        float4 v = w4[i];
        s += (double)fabsf(v.x) + (double)fabsf(v.y) +
             (double)fabsf(v.z) + (double)fabsf(v.w);
    }
    for (int o = 32; o > 0; o >>= 1) s += __shfl_down(s, o);
    __shared__ double sb[4];
    const int wid = threadIdx.x >> 6, lane = threadIdx.x & 63;
    if (lane == 0) sb[wid] = s;
    __syncthreads();
    if (threadIdx.x == 0) atomicAdd(acc, sb[0] + sb[1] + sb[2] + sb[3]);
}

__device__ __forceinline__ float sw_from_sum(const double* sump, int n) {
    float mean = (float)(*sump / (double)n);
    return 1.0f / fmaxf(mean, 1e-5f);   // sw = 1/max(mean|W|, Q_EPS)
}

// ---------------------------------------------------------------------------
// Kernel 2: ternary weight quantization -> int8 {-1,0,1}, row-major [O,K]
// ---------------------------------------------------------------------------
__global__ void wquant_kernel(const float4* __restrict__ w4,
                              const double* __restrict__ sump,
                              char4* __restrict__ wq4, int n4, int n) {
    const float s = sw_from_sum(sump, n);
    int i = blockIdx.x * blockDim.x + threadIdx.x;
    if (i >= n4) return;
    float4 v = w4[i];
    char4 q;
    q.x = (signed char)(int)fmaxf(-1.f, fminf(1.f, rintf(v.x * s)));
    q.y = (signed char)(int)fmaxf(-1.f, fminf(1.f, rintf(v.y * s)));
    q.z = (signed char)(int)fmaxf(-1.f, fminf(1.f, rintf(v.z * s)));
    q.w = (signed char)(int)fmaxf(-1.f, fminf(1.f, rintf(v.w * s)));
    wq4[i] = q;
}

// ---------------------------------------------------------------------------
// Kernel 3: fused RMSNorm + per-token int8 act quant.
// One block per token row (D=4096, 256 thr * 16 elems, kept in registers).
// Also writes rscale[m] = 1/(sx*sw) for the GEMM epilogue.
// ---------------------------------------------------------------------------
__global__ __launch_bounds__(256) void act_quant_kernel(
    const float* __restrict__ x, const float* __restrict__ nw,
    const double* __restrict__ sump, int wcount,
    signed char* __restrict__ hq, float* __restrict__ rscale, int D) {
    const int m = blockIdx.x;
    const int t = threadIdx.x;
    const float4* xr  = (const float4*)(x + (size_t)m * D);
    const float4* nw4 = (const float4*)nw;

    float4 v[4];
    float ss = 0.f;
#pragma unroll
    for (int i = 0; i < 4; ++i) {
        v[i] = xr[t + 256 * i];
        ss += v[i].x * v[i].x + v[i].y * v[i].y +
              v[i].z * v[i].z + v[i].w * v[i].w;
    }
    for (int o = 32; o > 0; o >>= 1) ss += __shfl_down(ss, o);
    __shared__ float sb[4];
    const int wid = t >> 6, lane = t & 63;
    if (lane == 0) sb[wid] = ss;
    __syncthreads();
    const float var  = (sb[0] + sb[1] + sb[2] + sb[3]) / (float)D;
    const float rstd = (float)(1.0 / sqrt((double)var + 1e-5));
    __syncthreads();   // sb re-used below

    float mx = 0.f;
#pragma unroll
    for (int i = 0; i < 4; ++i) {
        float4 g = nw4[t + 256 * i];
        v[i].x = v[i].x * rstd * g.x;
        v[i].y = v[i].y * rstd * g.y;
        v[i].z = v[i].z * rstd * g.z;
        v[i].w = v[i].w * rstd * g.w;
        mx = fmaxf(mx, fmaxf(fmaxf(fabsf(v[i].x), fabsf(v[i].y)),
                             fmaxf(fabsf(v[i].z), fabsf(v[i].w))));
    }
    for (int o = 32; o > 0; o >>= 1) mx = fmaxf(mx, __shfl_down(mx, o));
    if (lane == 0) sb[wid] = mx;
    __syncthreads();
    const float mxa   = fmaxf(fmaxf(sb[0], sb[1]), fmaxf(sb[2], sb[3]));
    const float scale = 127.0f / fmaxf(mxa, 1e-5f);

    char4* hq4 = (char4*)(hq + (size_t)m * D);
#pragma unroll
    for (int i = 0; i < 4; ++i) {
        char4 q;
        q.x = (signed char)(int)fmaxf(-128.f, fminf(127.f, rintf(v[i].x * scale)));
        q.y = (signed char)(int)fmaxf(-128.f, fminf(127.f, rintf(v[i].y * scale)));
        q.z = (signed char)(int)fmaxf(-128.f, fminf(127.f, rintf(v[i].z * scale)));
        q.w = (signed char)(int)fmaxf(-128.f, fminf(127.f, rintf(v[i].w * scale)));
        hq4[t + 256 * i] = q;
    }
    if (t == 0) {
        const float sw = sw_from_sum(sump, wcount);
        rscale[m] = 1.0f / (scale * sw);
    }
}

// ---------------------------------------------------------------------------
// Kernel 4: int8 GEMM  C[m,n] = sum_k A[m,k]*B[n,k]  (both K-contiguous, NT)
// 128x128 tile, BK=128 (32 barriers), 4 waves of 64x64, mfma_i32_32x32x32_i8,
// global_load_lds width-16 staging, XOR-swizzled LDS (k-quad q stored at slot
// q^(row&7)) so fragment reads are bank-balanced (8/bank = b128 minimum).
// Epilogue: out = (float)C * rscale[m].
// ---------------------------------------------------------------------------
__global__ __launch_bounds__(256) void gemm_i8_kernel(
    const signed char* __restrict__ A, const signed char* __restrict__ B,
    const float* __restrict__ rscale, float* __restrict__ out,
    int M, int N, int K) {
    constexpr int BM = 128, BN = 128, BK = 128;
    __shared__ signed char As[BM * BK];   // 16 KiB, row-major [128][128] swizzled
    __shared__ signed char Bs[BN * BK];   // 16 KiB

    const int tid  = threadIdx.x;
    const int wave = tid >> 6;
    const int lane = tid & 63;
    const int wm   = wave >> 1;           // wave row in 2x2 wave grid
    const int wn   = wave & 1;
    const int r32  = lane & 31;
    const int h    = lane >> 5;           // k-half selector

    const int m0 = blockIdx.y * BM;
    const int n0 = blockIdx.x * BN;

    v16i acc[2][2] = {};

    // staging: 16 chunks of 1024B each in As/Bs; wave w fills chunks 4w..4w+3.
    // chunk covers 8 rows x 128B; lane L -> LDS off L*16 = row (L>>3), slot
    // (L&7). Stored content: global k-quad (L&7)^(L>>3) (XOR swizzle; chunk is
    // 8-row aligned so row-in-chunk == global row & 7).
    const int srow = lane >> 3;                 // 0..7
    const int skb  = ((lane & 7) ^ srow) * 16;  // swizzled k-byte within BK
    const signed char* aSrc = A + (size_t)(m0 + wave * 32 + srow) * K + skb;
    const signed char* bSrc = B + (size_t)(n0 + wave * 32 + srow) * K + skb;

    for (int k0 = 0; k0 < K; k0 += BK) {
#pragma unroll
        for (int c = 0; c < 4; ++c) {
            load_lds16(aSrc + (size_t)(c * 8) * K + k0, &As[(wave * 4 + c) * 1024]);
            load_lds16(bSrc + (size_t)(c * 8) * K + k0, &Bs[(wave * 4 + c) * 1024]);
        }
        __syncthreads();   // drains vmcnt (global_load_lds) + barrier

#pragma unroll
        for (int ks = 0; ks < 4; ++ks) {
            // A-frag (32x32x32): row = lane&31, k = (lane>>5)*16 + j
            // k-quad q = ks*2 + h; swizzled slot = q ^ (row&7), row&7 == r32&7
            const int swz = ((ks * 2 + h) ^ (r32 & 7)) * 16;
            v4i af[2], bf[2];
#pragma unroll
            for (int mi = 0; mi < 2; ++mi)
                af[mi] = *(const v4i*)&As[(wm * 64 + mi * 32 + r32) * BK + swz];
#pragma unroll
            for (int ni = 0; ni < 2; ++ni)
                bf[ni] = *(const v4i*)&Bs[(wn * 64 + ni * 32 + r32) * BK + swz];
#pragma unroll
            for (int mi = 0; mi < 2; ++mi)
#pragma unroll
                for (int ni = 0; ni < 2; ++ni)
                    acc[mi][ni] = __builtin_amdgcn_mfma_i32_32x32x32_i8(
                        af[mi], bf[ni], acc[mi][ni], 0, 0, 0);
        }
        __syncthreads();
    }

    // epilogue: 32x32 C/D layout: col = lane&31, row = (reg&3)+8*(reg>>2)+4*h
#pragma unroll
    for (int mi = 0; mi < 2; ++mi) {
#pragma unroll
        for (int reg = 0; reg < 16; ++reg) {
            const int m = m0 + wm * 64 + mi * 32 + (reg & 3) + 8 * (reg >> 2) + 4 * h;
            const float rs = rscale[m];
            const size_t rowoff = (size_t)m * N + n0 + wn * 64 + r32;
#pragma unroll
            for (int ni = 0; ni < 2; ++ni)
                out[rowoff + ni * 32] = (float)acc[mi][ni][reg] * rs;
        }
    }
}

// ---------------------------------------------------------------------------
extern "C" void kernel_launch(void* const* d_in, const int* in_sizes, int n_in,
                              void* d_out, int out_size, void* d_ws, size_t ws_size,
                              hipStream_t stream) {
    const float* x  = (const float*)d_in[0];   // [B,S,D] fp32
    const float* nw = (const float*)d_in[1];   // [D]
    const float* w  = (const float*)d_in[2];   // [O,D]
    const int D = in_sizes[1];
    const int M = in_sizes[0] / D;             // B*S tokens
    const int O = in_sizes[2] / D;
    const int WN = O * D;                      // weight element count

    char* ws = (char*)d_ws;
    double* d_sum    = (double*)(ws + 0);
    float*  d_rscale = (float*)(ws + 128);
    size_t off = 128 + (size_t)M * sizeof(float);
    off = (off + 255) & ~(size_t)255;
    signed char* d_wq = (signed char*)(ws + off);
    off += (size_t)WN;
    off = (off + 255) & ~(size_t)255;
    signed char* d_hq = (signed char*)(ws + off);

    hipMemsetAsync(d_sum, 0, sizeof(double), stream);

    wabs_sum_kernel<<<4096, 256, 0, stream>>>((const float4*)w, d_sum, WN / 4);

    wquant_kernel<<<(WN / 4 + 255) / 256, 256, 0, stream>>>(
        (const float4*)w, d_sum, (char4*)d_wq, WN / 4, WN);

    act_quant_kernel<<<M, 256, 0, stream>>>(x, nw, d_sum, WN, d_hq, d_rscale, D);

    dim3 grid(O / 128, M / 128);
    gemm_i8_kernel<<<grid, 256, 0, stream>>>(d_hq, d_wq, d_rscale,
                                             (float*)d_out, M, O, D);
}